// Round 1
// baseline (173.371 us; speedup 1.0000x reference)
//
#include <hip/hip_runtime.h>
#include <math.h>

#define NAANCH 3
#define NCLS 80
#define BATCH 16
#define MTGT 32
#define NTGT (BATCH * MTGT)   // 512 targets total
#define CH (5 + NCLS)         // 85 channels per anchor

__device__ __forceinline__ float bce0(float x) {
    // bce with target 0: max(x,0) + log1p(exp(-|x|))
    return fmaxf(x, 0.0f) + log1pf(expf(-fabsf(x)));
}
__device__ __forceinline__ float bce(float x, float t) {
    return fmaxf(x, 0.0f) - x * t + log1pf(expf(-fabsf(x)));
}

// ws layout (floats):
// ws[0..2]  : per-scale obj bce sum (zeroed here, atomically added by obj_kernel)
// ws[3..5]  : per-scale lbox sum
// ws[6..8]  : per-scale raw nb (sum of maskf)
// ws[9..11] : per-scale lcls sum
// ws[12..14]: per-scale obj correction (sum of -logit over unique masked cells)
__global__ void assign_kernel(const float* __restrict__ p0,
                              const float* __restrict__ p1,
                              const float* __restrict__ p2,
                              const float* __restrict__ targets,
                              const float* __restrict__ anchors,
                              const float* __restrict__ image_size,
                              float* __restrict__ ws) {
    const int s = blockIdx.x;          // scale 0..2
    const int j = threadIdx.x;         // target 0..511
    const int H = (s == 0) ? 80 : ((s == 1) ? 40 : 20);
    const int W = H;
    const float* pi = (s == 0) ? p0 : ((s == 1) ? p1 : p2);

    const float img0 = image_size[0], img1 = image_size[1];
    const float stride0 = img0 / (float)H;   // y-stride
    const float stride1 = img1 / (float)W;   // x-stride
    const float gx = 1.0f / stride1;
    const float gy = 1.0f / stride0;

    __shared__ int   keys[NTGT];
    __shared__ unsigned char mk[NTGT];
    __shared__ float wpart[4][8];

    const float t0 = targets[j * 6 + 0];
    const float t1 = targets[j * 6 + 1];
    const float tx = targets[j * 6 + 2] * gx;
    const float ty = targets[j * 6 + 3] * gy;
    const float gw = targets[j * 6 + 4] * gx;
    const float gh = targets[j * 6 + 5] * gy;

    // anchor-vs-target wh IoU; argmax with first-max semantics
    float best = -1.0f; int abest = 0;
    for (int k = 0; k < NAANCH; ++k) {
        float aw = anchors[(s * NAANCH + k) * 2 + 0] / stride1;
        float ah = anchors[(s * NAANCH + k) * 2 + 1] / stride0;
        float inter = fminf(aw, gw) * fminf(ah, gh);
        float uni = aw * ah + gw * gh - inter;
        float iou = inter / uni;
        if (iou > best) { best = iou; abest = k; }
    }
    const bool  mask  = best > 0.6f;
    const float maskf = mask ? 1.0f : 0.0f;

    int b  = mask ? (int)t0 : 0;
    const int c = (int)t1;
    int gi = mask ? (int)tx : 0;
    int gj = mask ? (int)ty : 0;
    const int a_s = mask ? abest : 0;
    gi = min(max(gi, 0), W - 1);
    gj = min(max(gj, 0), H - 1);
    b  = min(max(b, 0), BATCH - 1);

    float lbox_t = 0.0f, lcls_t = 0.0f, ps4 = 0.0f;
    const int key = ((b * NAANCH + a_s) * H + gj) * W + gi;

    if (mask) {
        const int HW = H * W;
        const float* base = pi + (size_t)(b * (NAANCH * CH) + a_s * CH) * HW + gj * W + gi;
        const float ps0 = base[0 * HW];
        const float ps1 = base[1 * HW];
        const float ps2 = base[2 * HW];
        const float ps3 = base[3 * HW];
        ps4 = base[4 * HW];

        const float aw = anchors[(s * NAANCH + a_s) * 2 + 0] / stride1;
        const float ah = anchors[(s * NAANCH + a_s) * 2 + 1] / stride0;

        const float pxc = 1.0f / (1.0f + expf(-ps0));
        const float pyc = 1.0f / (1.0f + expf(-ps1));
        const float pw  = fminf(expf(ps2), 1000.0f) * aw;
        const float ph  = fminf(expf(ps3), 1000.0f) * ah;
        const float txc = tx - floorf(tx);
        const float tyc = ty - floorf(ty);

        const float px1 = pxc - pw * 0.5f, py1 = pyc - ph * 0.5f;
        const float px2 = pxc + pw * 0.5f, py2 = pyc + ph * 0.5f;
        const float qx1 = txc - gw * 0.5f, qy1 = tyc - gh * 0.5f;
        const float qx2 = txc + gw * 0.5f, qy2 = tyc + gh * 0.5f;
        const float iw = fmaxf(fminf(px2, qx2) - fmaxf(px1, qx1), 0.0f);
        const float ih = fmaxf(fminf(py2, qy2) - fmaxf(py1, qy1), 0.0f);
        const float inter = iw * ih;
        const float uni = pw * ph + gw * gh - inter + 1e-7f;
        const float iou = inter / uni;
        const float cw = fmaxf(px2, qx2) - fminf(px1, qx1);
        const float chh = fmaxf(py2, qy2) - fminf(py1, qy1);
        const float carea = cw * chh + 1e-7f;
        const float giou = iou - (carea - uni) / carea;
        lbox_t = 1.0f - giou;

        const int ci = c - 1;
        float sum = 0.0f;
        for (int k = 0; k < NCLS; ++k) {
            float x = base[(5 + k) * HW];
            sum += bce(x, (k == ci) ? 1.0f : 0.0f);
        }
        lcls_t = sum;
    }

    keys[j] = key; mk[j] = mask ? 1 : 0;
    __syncthreads();

    float corr = 0.0f;
    if (mask) {
        bool dup = false;
        for (int j2 = 0; j2 < j; ++j2)
            if (mk[j2] && keys[j2] == key) { dup = true; break; }
        if (!dup) corr = -ps4;   // bce(x,1) - bce(x,0) = -x, once per unique cell
    }

    // block reduce 4 quantities over 512 threads (8 waves)
    float vals[4] = { lbox_t, maskf, lcls_t, corr };
    const int lane = j & 63, wid = j >> 6;
    for (int q = 0; q < 4; ++q) {
        float v = vals[q];
        for (int off = 32; off > 0; off >>= 1) v += __shfl_down(v, off, 64);
        if (lane == 0) wpart[q][wid] = v;
    }
    __syncthreads();
    if (j == 0) {
        float acc[4];
        for (int q = 0; q < 4; ++q) {
            float v = 0.0f;
            for (int w2 = 0; w2 < 8; ++w2) v += wpart[q][w2];
            acc[q] = v;
        }
        ws[0 + s]  = 0.0f;     // obj accumulator for obj_kernel (runs after, stream order)
        ws[3 + s]  = acc[0];
        ws[6 + s]  = acc[1];
        ws[9 + s]  = acc[2];
        ws[12 + s] = acc[3];
    }
}

template <int HW>
__device__ __forceinline__ float obj_elem(const float* __restrict__ pi, int e) {
    int ba = e / HW;
    int hw = e - ba * HW;
    int b  = ba / NAANCH;
    int a  = ba - b * NAANCH;
    float x = pi[(size_t)(b * (NAANCH * CH) + a * CH + 4) * HW + hw];
    return bce0(x);
}

// blocks 0..1199 -> scale 0 (307200 el), 1200..1499 -> scale 1 (76800), 1500..1574 -> scale 2 (19200)
__global__ void obj_kernel(const float* __restrict__ p0,
                           const float* __restrict__ p1,
                           const float* __restrict__ p2,
                           float* __restrict__ ws) {
    const int blk = blockIdx.x;
    const int tid = threadIdx.x;
    float v; int s;
    if (blk < 1200)      { s = 0; v = obj_elem<6400>(p0, blk * 256 + tid); }
    else if (blk < 1500) { s = 1; v = obj_elem<1600>(p1, (blk - 1200) * 256 + tid); }
    else                 { s = 2; v = obj_elem<400 >(p2, (blk - 1500) * 256 + tid); }

    for (int off = 32; off > 0; off >>= 1) v += __shfl_down(v, off, 64);
    __shared__ float part[4];
    const int lane = tid & 63, wid = tid >> 6;
    if (lane == 0) part[wid] = v;
    __syncthreads();
    if (tid == 0) {
        atomicAdd(&ws[s], part[0] + part[1] + part[2] + part[3]);
    }
}

__global__ void finalize_kernel(const float* __restrict__ ws, float* __restrict__ out) {
    if (threadIdx.x == 0 && blockIdx.x == 0) {
        const float Ns[3] = { 307200.0f, 76800.0f, 19200.0f };
        float lbox = 0.0f, lobj = 0.0f, lcls = 0.0f;
        for (int s = 0; s < 3; ++s) {
            float nb = fmaxf(ws[6 + s], 1.0f);
            lbox += ws[3 + s] / nb;
            lobj += (ws[0 + s] + ws[12 + s]) / Ns[s];
            lcls += ws[9 + s] / (nb * (float)NCLS);
        }
        lbox *= 3.54f; lobj *= 64.3f; lcls *= 37.4f;
        out[0] = lbox + lobj + lcls;
        out[1] = lbox;
        out[2] = lobj;
        out[3] = lcls;
    }
}

extern "C" void kernel_launch(void* const* d_in, const int* in_sizes, int n_in,
                              void* d_out, int out_size, void* d_ws, size_t ws_size,
                              hipStream_t stream) {
    const float* p0       = (const float*)d_in[0];
    const float* p1       = (const float*)d_in[1];
    const float* p2       = (const float*)d_in[2];
    const float* targets  = (const float*)d_in[3];
    const float* anchors  = (const float*)d_in[4];
    const float* img_size = (const float*)d_in[5];
    float* out = (float*)d_out;
    float* ws  = (float*)d_ws;

    assign_kernel<<<3, NTGT, 0, stream>>>(p0, p1, p2, targets, anchors, img_size, ws);
    obj_kernel<<<1575, 256, 0, stream>>>(p0, p1, p2, ws);
    finalize_kernel<<<1, 64, 0, stream>>>(ws, out);
}

// Round 2
// 154.959 us; speedup vs baseline: 1.1188x; 1.1188x over previous
//
#include <hip/hip_runtime.h>
#include <math.h>

#define NAANCH 3
#define NCLS 80
#define BATCH 16
#define NTGT 512          // 16*32 targets
#define CH 85             // 5 + NCLS channels per anchor

// vec4 element counts per scale for the obj pass
#define V4_S0 76800       // 16*3*6400/4
#define V4_S1 19200       // 16*3*1600/4
#define V4_S2 4800        // 16*3*400/4
#define V4_TOT (V4_S0 + V4_S1 + V4_S2)   // 100800
#define OBJ_BLOCKS 197    // ceil(100800/512)

__device__ __forceinline__ float bce0(float x) {
    // bce(x, 0) = max(x,0) + log1p(exp(-|x|))
    return fmaxf(x, 0.0f) + log1pf(expf(-fabsf(x)));
}

__device__ __forceinline__ float wave_sum(float v) {
    for (int off = 32; off > 0; off >>= 1) v += __shfl_down(v, off, 64);
    return v;
}

// ws layout (floats):
// ws[3..5]   per-scale lbox sum        (assign blocks)
// ws[6..8]   per-scale raw nb          (assign blocks)
// ws[9..11]  per-scale lcls sum        (assign blocks)
// ws[12..14] per-scale obj correction  (assign blocks)
// ws[16 + blk*3 + s]  per-obj-block partial bce0 sums, blk in [0,197)
__global__ void fused_kernel(const float* __restrict__ p0,
                             const float* __restrict__ p1,
                             const float* __restrict__ p2,
                             const float* __restrict__ targets,
                             const float* __restrict__ anchors,
                             const float* __restrict__ image_size,
                             float* __restrict__ ws) {
    const int tid  = threadIdx.x;
    const int lane = tid & 63;
    const int wid  = tid >> 6;

    __shared__ int   sh_key[NTGT];
    __shared__ int   sh_off[NTGT];
    __shared__ int   sh_ci[NTGT];
    __shared__ unsigned char sh_mk[NTGT];
    __shared__ float red[4][8];

    if (blockIdx.x < 3) {
        // ---------------- assign path: one block per scale ----------------
        const int s = blockIdx.x;
        const int j = tid;                // target 0..511
        const int H = (s == 0) ? 80 : ((s == 1) ? 40 : 20);
        const int W = H;
        const int HW = H * W;
        const float* pi = (s == 0) ? p0 : ((s == 1) ? p1 : p2);

        const float stride0 = image_size[0] / (float)H;
        const float stride1 = image_size[1] / (float)W;
        const float gx = 1.0f / stride1;
        const float gy = 1.0f / stride0;

        const float t0 = targets[j * 6 + 0];
        const float t1 = targets[j * 6 + 1];
        const float tx = targets[j * 6 + 2] * gx;
        const float ty = targets[j * 6 + 3] * gy;
        const float gw = targets[j * 6 + 4] * gx;
        const float gh = targets[j * 6 + 5] * gy;

        // anchor-vs-target wh IoU, first-max argmax
        float best = -1.0f; int abest = 0;
        for (int k = 0; k < NAANCH; ++k) {
            float aw = anchors[(s * NAANCH + k) * 2 + 0] / stride1;
            float ah = anchors[(s * NAANCH + k) * 2 + 1] / stride0;
            float inter = fminf(aw, gw) * fminf(ah, gh);
            float uni = aw * ah + gw * gh - inter;
            float iou = inter / uni;
            if (iou > best) { best = iou; abest = k; }
        }
        const bool  mask  = best > 0.6f;
        const float maskf = mask ? 1.0f : 0.0f;

        int b  = mask ? (int)t0 : 0;
        const int c = (int)t1;
        int gi = mask ? (int)tx : 0;
        int gj = mask ? (int)ty : 0;
        const int a_s = mask ? abest : 0;
        gi = min(max(gi, 0), W - 1);
        gj = min(max(gj, 0), H - 1);
        b  = min(max(b, 0), BATCH - 1);

        const int key = ((b * NAANCH + a_s) * H + gj) * W + gi;
        const int off = (b * (NAANCH * CH) + a_s * CH) * HW + gj * W + gi;

        float lbox_t = 0.0f, ps4 = 0.0f;
        if (mask) {
            const float ps0 = pi[off + 0 * HW];
            const float ps1 = pi[off + 1 * HW];
            const float ps2 = pi[off + 2 * HW];
            const float ps3 = pi[off + 3 * HW];
            ps4 = pi[off + 4 * HW];

            const float aw = anchors[(s * NAANCH + a_s) * 2 + 0] / stride1;
            const float ah = anchors[(s * NAANCH + a_s) * 2 + 1] / stride0;

            const float pxc = 1.0f / (1.0f + expf(-ps0));
            const float pyc = 1.0f / (1.0f + expf(-ps1));
            const float pw  = fminf(expf(ps2), 1000.0f) * aw;
            const float ph  = fminf(expf(ps3), 1000.0f) * ah;
            const float txc = tx - floorf(tx);
            const float tyc = ty - floorf(ty);

            const float px1 = pxc - pw * 0.5f, py1 = pyc - ph * 0.5f;
            const float px2 = pxc + pw * 0.5f, py2 = pyc + ph * 0.5f;
            const float qx1 = txc - gw * 0.5f, qy1 = tyc - gh * 0.5f;
            const float qx2 = txc + gw * 0.5f, qy2 = tyc + gh * 0.5f;
            const float iw = fmaxf(fminf(px2, qx2) - fmaxf(px1, qx1), 0.0f);
            const float ih = fmaxf(fminf(py2, qy2) - fmaxf(py1, qy1), 0.0f);
            const float inter = iw * ih;
            const float uni = pw * ph + gw * gh - inter + 1e-7f;
            const float iou = inter / uni;
            const float cw  = fmaxf(px2, qx2) - fminf(px1, qx1);
            const float chh = fmaxf(py2, qy2) - fminf(py1, qy1);
            const float carea = cw * chh + 1e-7f;
            lbox_t = 1.0f - (iou - (carea - uni) / carea);
        }

        sh_key[j] = key;
        sh_off[j] = off;
        sh_ci[j]  = c - 1;
        sh_mk[j]  = mask ? 1 : 0;
        __syncthreads();

        // dedup: obj correction -x once per unique masked cell
        float corr = 0.0f;
        if (mask) {
            bool dup = false;
            for (int j2 = 0; j2 < j; ++j2)
                if (sh_mk[j2] && sh_key[j2] == key) { dup = true; break; }
            if (!dup) corr = -ps4;   // bce(x,1) - bce(x,0) = -x
        }

        float v0 = wave_sum(lbox_t);
        float v1 = wave_sum(maskf);
        float v2 = wave_sum(corr);
        if (lane == 0) { red[0][wid] = v0; red[1][wid] = v1; red[2][wid] = v2; }
        __syncthreads();

        // phase 2: lane-parallel class BCE; wave wid handles targets wid, wid+8, ...
        float lcls_w = 0.0f;
        for (int j2 = wid; j2 < NTGT; j2 += 8) {
            if (!sh_mk[j2]) continue;               // wave-uniform branch
            const int toff = sh_off[j2];
            const int ci   = sh_ci[j2];
            const int k1 = lane;
            float x1 = pi[toff + (5 + k1) * HW];
            float c1 = bce0(x1) - ((k1 == ci) ? x1 : 0.0f);
            float c2 = 0.0f;
            if (lane < NCLS - 64) {                 // classes 64..79
                const int k2 = 64 + lane;
                float x2 = pi[toff + (5 + k2) * HW];
                c2 = bce0(x2) - ((k2 == ci) ? x2 : 0.0f);
            }
            float tsum = wave_sum(c1 + c2);
            if (lane == 0) lcls_w += tsum;
        }
        if (lane == 0) red[3][wid] = lcls_w;
        __syncthreads();

        if (tid == 0) {
            float acc[4] = {0.f, 0.f, 0.f, 0.f};
            for (int w = 0; w < 8; ++w) {
                acc[0] += red[0][w]; acc[1] += red[1][w];
                acc[2] += red[2][w]; acc[3] += red[3][w];
            }
            ws[3 + s]  = acc[0];   // lbox sum
            ws[6 + s]  = acc[1];   // nb raw
            ws[9 + s]  = acc[3];   // lcls sum
            ws[12 + s] = acc[2];   // obj correction
        }
    } else {
        // ---------------- obj path: float4 over objectness planes ----------------
        const int vb = (blockIdx.x - 3) * 512 + tid;   // vec4 index
        float a0 = 0.f, a1 = 0.f, a2 = 0.f;
        if (vb < V4_TOT) {
            const float4* addr; int hw4; int sflag;
            if (vb < V4_S0) {
                const int u = vb;
                const int ba = u / 1600;  hw4 = u - ba * 1600;
                const int b = ba / 3, a = ba - 3 * b;
                addr = (const float4*)(p0 + (size_t)((b * NAANCH + a) * CH + 4) * 6400);
                sflag = 0;
            } else if (vb < V4_S0 + V4_S1) {
                const int u = vb - V4_S0;
                const int ba = u / 400;   hw4 = u - ba * 400;
                const int b = ba / 3, a = ba - 3 * b;
                addr = (const float4*)(p1 + (size_t)((b * NAANCH + a) * CH + 4) * 1600);
                sflag = 1;
            } else {
                const int u = vb - V4_S0 - V4_S1;
                const int ba = u / 100;   hw4 = u - ba * 100;
                const int b = ba / 3, a = ba - 3 * b;
                addr = (const float4*)(p2 + (size_t)((b * NAANCH + a) * CH + 4) * 400);
                sflag = 2;
            }
            float4 x = addr[hw4];
            float v = bce0(x.x) + bce0(x.y) + bce0(x.z) + bce0(x.w);
            if (sflag == 0) a0 = v; else if (sflag == 1) a1 = v; else a2 = v;
        }
        a0 = wave_sum(a0); a1 = wave_sum(a1); a2 = wave_sum(a2);
        if (lane == 0) { red[0][wid] = a0; red[1][wid] = a1; red[2][wid] = a2; }
        __syncthreads();
        if (tid == 0) {
            float s0 = 0.f, s1 = 0.f, s2 = 0.f;
            for (int w = 0; w < 8; ++w) { s0 += red[0][w]; s1 += red[1][w]; s2 += red[2][w]; }
            const int blk = blockIdx.x - 3;
            ws[16 + blk * 3 + 0] = s0;
            ws[16 + blk * 3 + 1] = s1;
            ws[16 + blk * 3 + 2] = s2;
        }
    }
}

__global__ void finalize_kernel(const float* __restrict__ ws, float* __restrict__ out) {
    const int t = threadIdx.x;         // 256 threads
    const int lane = t & 63, wid = t >> 6;
    float o0 = 0.f, o1 = 0.f, o2 = 0.f;
    if (t < OBJ_BLOCKS) {
        o0 = ws[16 + t * 3 + 0];
        o1 = ws[16 + t * 3 + 1];
        o2 = ws[16 + t * 3 + 2];
    }
    o0 = wave_sum(o0); o1 = wave_sum(o1); o2 = wave_sum(o2);
    __shared__ float part[3][4];
    if (lane == 0) { part[0][wid] = o0; part[1][wid] = o1; part[2][wid] = o2; }
    __syncthreads();
    if (t == 0) {
        float obj[3];
        for (int s = 0; s < 3; ++s)
            obj[s] = part[s][0] + part[s][1] + part[s][2] + part[s][3];
        const float Ns[3] = { 307200.0f, 76800.0f, 19200.0f };
        float lbox = 0.f, lobj = 0.f, lcls = 0.f;
        for (int s = 0; s < 3; ++s) {
            float nb = fmaxf(ws[6 + s], 1.0f);
            lbox += ws[3 + s] / nb;
            lobj += (obj[s] + ws[12 + s]) / Ns[s];
            lcls += ws[9 + s] / (nb * (float)NCLS);
        }
        lbox *= 3.54f; lobj *= 64.3f; lcls *= 37.4f;
        out[0] = lbox + lobj + lcls;
        out[1] = lbox;
        out[2] = lobj;
        out[3] = lcls;
    }
}

extern "C" void kernel_launch(void* const* d_in, const int* in_sizes, int n_in,
                              void* d_out, int out_size, void* d_ws, size_t ws_size,
                              hipStream_t stream) {
    const float* p0       = (const float*)d_in[0];
    const float* p1       = (const float*)d_in[1];
    const float* p2       = (const float*)d_in[2];
    const float* targets  = (const float*)d_in[3];
    const float* anchors  = (const float*)d_in[4];
    const float* img_size = (const float*)d_in[5];
    float* out = (float*)d_out;
    float* ws  = (float*)d_ws;

    fused_kernel<<<3 + OBJ_BLOCKS, 512, 0, stream>>>(p0, p1, p2, targets, anchors, img_size, ws);
    finalize_kernel<<<1, 256, 0, stream>>>(ws, out);
}